// Round 8
// baseline (464.654 us; speedup 1.0000x reference)
//
#include <hip/hip_runtime.h>
#include <hip/hip_cooperative_groups.h>
#include <math.h>

// R8: single cooperative kernel. R5 bodies (fastest: 171.8us) with the 6
// dispatches replaced by 5 grid.sync()s. R6 (s_load weights) and R7 (rider
// load-balancing) both regressed; dispatch-boundary drain is the remaining
// structural overhead we control.
// Phases: P0 minmax+zero | P1 ds512 + c1peg256 + fc2/klt3 riders |
//         P2 bnpad (512 half-units) | P3 mid3x3 512 | P4 back 1024 | P5 final.

namespace cg = cooperative_groups;

#define HW 784
#define NB 4
#define STAGE 100

struct Params {
  const float *x, *w_ds, *a_ds, *lap_ds, *w_c1, *a_c1, *lap_c1;
  const float *w_c2, *a_c2, *lap_c2, *w_c3, *a_c3, *lap_c3;
  const float *peg_w, *g1, *b1, *g2, *b2, *g3, *b3, *gds, *bds;
  float *f_c2, *mmbuf, *A, *T2, *T2b, *T3, *out;
  double *dstat;
};

// ---------------- wave/block reduction helpers (wave64) --------------------
__device__ __forceinline__ float wredMax(float v){
  for (int o = 32; o > 0; o >>= 1) v = fmaxf(v, __shfl_down(v, o, 64));
  return v;
}
__device__ __forceinline__ float wredMin(float v){
  for (int o = 32; o > 0; o >>= 1) v = fminf(v, __shfl_down(v, o, 64));
  return v;
}
__device__ __forceinline__ double wredSumD(double v){
  for (int o = 32; o > 0; o >>= 1) v += __shfl_down(v, o, 64);
  return v;
}
__device__ float blockMin4(float v){
  __shared__ float shn[4];
  __syncthreads();
  v = wredMin(v);
  if ((threadIdx.x & 63) == 0) shn[threadIdx.x >> 6] = v;
  __syncthreads();
  return fminf(fminf(shn[0], shn[1]), fminf(shn[2], shn[3]));
}
__device__ float blockMax4(float v){
  __shared__ float shx[4];
  __syncthreads();
  v = wredMax(v);
  if ((threadIdx.x & 63) == 0) shx[threadIdx.x >> 6] = v;
  __syncthreads();
  return fmaxf(fmaxf(shx[0], shx[1]), fmaxf(shx[2], shx[3]));
}
__device__ void stats4(float v0, float v1, float v2, float v3,
                       double* sumP, double* sqP, int oc0){
  __shared__ double sred[4][8];
  __syncthreads();
  const int w = threadIdx.x >> 6;
  float vv[4] = {v0, v1, v2, v3};
  #pragma unroll
  for (int i = 0; i < 4; i++){
    double d = (double)vv[i];
    double s = wredSumD(d);
    double q = wredSumD(d * d);
    if ((threadIdx.x & 63) == 0){ sred[w][i] = s; sred[w][4 + i] = q; }
  }
  __syncthreads();
  if (threadIdx.x < 8){
    double tot = sred[0][threadIdx.x] + sred[1][threadIdx.x]
               + sred[2][threadIdx.x] + sred[3][threadIdx.x];
    int i = threadIdx.x & 3;
    if (threadIdx.x < 4) atomicAdd(&sumP[oc0 + i], tot);
    else                 atomicAdd(&sqP[oc0 + i],  tot);
  }
}
__device__ void stats2(float v0, float v1, double* sumP, double* sqP, int oc0){
  __shared__ double sred2[4][4];
  __syncthreads();
  const int w = threadIdx.x >> 6;
  float vv[2] = {v0, v1};
  #pragma unroll
  for (int i = 0; i < 2; i++){
    double d = (double)vv[i];
    double s = wredSumD(d);
    double q = wredSumD(d * d);
    if ((threadIdx.x & 63) == 0){ sred2[w][i] = s; sred2[w][2 + i] = q; }
  }
  __syncthreads();
  if (threadIdx.x < 4){
    double tot = sred2[0][threadIdx.x] + sred2[1][threadIdx.x]
               + sred2[2][threadIdx.x] + sred2[3][threadIdx.x];
    int i = threadIdx.x & 1;
    if (threadIdx.x < 2) atomicAdd(&sumP[oc0 + i], tot);
    else                 atomicAdd(&sqP[oc0 + i],  tot);
  }
}
__device__ void klAccum(float se, float sel, float sef, float sq, double* dst){
  __shared__ double kls[4][4];
  __syncthreads();
  const int w = threadIdx.x >> 6;
  double a0 = wredSumD((double)se);
  double a1 = wredSumD((double)sel);
  double a2 = wredSumD((double)sef);
  double a3 = wredSumD((double)sq);
  if ((threadIdx.x & 63) == 0){
    kls[w][0] = a0; kls[w][1] = a1; kls[w][2] = a2; kls[w][3] = a3;
  }
  __syncthreads();
  if (threadIdx.x < 4){
    double tot = kls[0][threadIdx.x] + kls[1][threadIdx.x]
               + kls[2][threadIdx.x] + kls[3][threadIdx.x];
    atomicAdd(&dst[threadIdx.x], tot);
  }
}
__device__ __forceinline__ float reconv(float vv, float mn, float rng,
                                        const float* saff){
  float q = (vv - mn) / rng * 100.0f;
  int idx = (int)floorf(q);
  float nv = 0.0f;
  if (idx < STAGE){
    int ci = idx < 0 ? 0 : (idx > STAGE - 1 ? STAGE - 1 : idx);
    nv = vv * saff[ci];
  }
  return nv;
}
__device__ __forceinline__ void mmReduce(const float* mmbuf, int tens,
                                         float& mn, float& mx){
  mn = 3.402823466e38f; mx = -3.402823466e38f;
  #pragma unroll
  for (int k = 0; k < 16; k++){
    mn = fminf(mn, mmbuf[tens * 32 + k]);
    mx = fmaxf(mx, mmbuf[tens * 32 + 16 + k]);
  }
}

// ---- P1 unit: adder_ds (u in [0,512)), 8 oc x 196-px chunk (R5 body) ------
__device__ void dsUnit(int u, const Params& p){
  const int t = threadIdx.x;
  const int chunk = u & 3, og = (u >> 2) & 31, b = u >> 7;
  const int oc0 = og * 8;
  __shared__ float ds_saff[STAGE];
  __shared__ float ds_sw[1024];
  __syncthreads();
  if (t < STAGE) ds_saff[t] = p.a_ds[t];
  float mn, mx; mmReduce(p.mmbuf, 0, mn, mx);
  const float rng = mx - mn;
  __syncthreads();
  for (int k = t; k < 1024; k += 256)
    ds_sw[k] = reconv(p.w_ds[oc0 * 128 + k], mn, rng, ds_saff);
  __syncthreads();

  const int px = chunk * 196 + t;
  float v0=0,v1=0,v2=0,v3=0,v4=0,v5=0,v6=0,v7=0;
  if (t < 196){
    const float* xp = p.x + (size_t)b * 128 * HW + px;
    float c0=0,c1=0,c2=0,c3=0,c4=0,c5=0,c6=0,c7=0;
    #pragma unroll 4
    for (int c = 0; c < 128; c++){
      float xv = xp[(size_t)c * HW];
      c0 += fabsf(xv - ds_sw[c]);
      c1 += fabsf(xv - ds_sw[128 + c]);
      c2 += fabsf(xv - ds_sw[256 + c]);
      c3 += fabsf(xv - ds_sw[384 + c]);
      c4 += fabsf(xv - ds_sw[512 + c]);
      c5 += fabsf(xv - ds_sw[640 + c]);
      c6 += fabsf(xv - ds_sw[768 + c]);
      c7 += fabsf(xv - ds_sw[896 + c]);
    }
    v0=-c0; v1=-c1; v2=-c2; v3=-c3; v4=-c4; v5=-c5; v6=-c6; v7=-c7;
    float* op = p.A + ((size_t)(b * 256 + oc0)) * HW + px;
    op[0]=v0; op[HW]=v1; op[2*HW]=v2; op[3*HW]=v3;
    op[4*HW]=v4; op[5*HW]=v5; op[6*HW]=v6; op[7*HW]=v7;
  }
  stats4(v0, v1, v2, v3, p.dstat + 0, p.dstat + 256, oc0);
  stats4(v4, v5, v6, v7, p.dstat + 0, p.dstat + 256, oc0 + 4);

  if (chunk == 0 && b == 0){           // KL rider tensor 0 (32 units)
    float se = 0, sel = 0, sef = 0, sq = 0;
    for (int k = t; k < 1024; k += 256){
      float l = p.lap_ds[oc0 * 128 + k];
      float e = expf(l);
      se += e; sel += e * l; sef += e * ds_sw[k];
      sq += expf(ds_sw[k]);
    }
    klAccum(se, sel, sef, sq, p.dstat + 1280 + 0);
  }
}

// ---- P1 unit: adder_c1 + PEG (a in [0,256)) (R5 body) ---------------------
__device__ void c1Unit(int a, const Params& p){
  const int t = threadIdx.x;
  const int rc = a & 3, og = (a >> 2) & 15, b = a >> 6;
  const int oc0 = og * 4;
  __shared__ float c1_saff[STAGE];
  __shared__ float c1_swc[512];
  __shared__ float c1_swp[36];
  __shared__ float c1_sT1[4][256];
  if (t < STAGE) c1_saff[t] = p.a_c1[t];
  if (t >= 128 && t < 164) c1_swp[t - 128] = p.peg_w[oc0 * 9 + (t - 128)];
  float mn, mx; mmReduce(p.mmbuf, 1, mn, mx);
  const float rng = mx - mn;
  __syncthreads();
  for (int k = t; k < 512; k += 256)
    c1_swc[k] = reconv(p.w_c1[oc0 * 128 + k], mn, rng, c1_saff);
  __syncthreads();

  if (t < 252){
    const int rr = t / 28;
    const int col = t - rr * 28;
    const int wr = rc * 7 - 1 + rr;
    float tv0 = 0, tv1 = 0, tv2 = 0, tv3 = 0;
    if (wr >= 0 && wr < 28){
      const float* xp = p.x + (size_t)b * 128 * HW + wr * 28 + col;
      float c0 = 0, c1 = 0, c2 = 0, c3 = 0;
      #pragma unroll 4
      for (int c = 0; c < 128; c++){
        float xv = xp[(size_t)c * HW];
        c0 += fabsf(xv - c1_swc[c]);
        c1 += fabsf(xv - c1_swc[128 + c]);
        c2 += fabsf(xv - c1_swc[256 + c]);
        c3 += fabsf(xv - c1_swc[384 + c]);
      }
      tv0 = -c0; tv1 = -c1; tv2 = -c2; tv3 = -c3;
    }
    c1_sT1[0][t] = tv0; c1_sT1[1][t] = tv1;
    c1_sT1[2][t] = tv2; c1_sT1[3][t] = tv3;
  }
  __syncthreads();
  float v0 = 0, v1 = 0, v2 = 0, v3 = 0;
  if (t < 196){
    const int r = t / 28, col = t - r * 28;
    float c0 = 0, c1 = 0, c2 = 0, c3 = 0;
    #pragma unroll
    for (int ky = 0; ky < 3; ky++){
      #pragma unroll
      for (int kx = 0; kx < 3; kx++){
        int cc = col + kx - 1;
        bool ok = (cc >= 0) && (cc < 28);
        int idx = ok ? ((r + ky) * 28 + cc) : 0;
        float p0 = ok ? c1_sT1[0][idx] : 0.0f;
        float p1 = ok ? c1_sT1[1][idx] : 0.0f;
        float p2 = ok ? c1_sT1[2][idx] : 0.0f;
        float p3 = ok ? c1_sT1[3][idx] : 0.0f;
        int wk = ky * 3 + kx;
        c0 += fabsf(p0 - c1_swp[wk]);
        c1 += fabsf(p1 - c1_swp[9 + wk]);
        c2 += fabsf(p2 - c1_swp[18 + wk]);
        c3 += fabsf(p3 - c1_swp[27 + wk]);
      }
    }
    v0 = -c0; v1 = -c1; v2 = -c2; v3 = -c3;
    const int opx = (rc * 7 + r) * 28 + col;
    float* op = p.T2 + ((size_t)(b * 64 + oc0)) * HW + opx;
    op[0] = v0; op[HW] = v1; op[2 * HW] = v2; op[3 * HW] = v3;
  }
  stats4(v0, v1, v2, v3, p.dstat + 512, p.dstat + 576, oc0);

  if (b == 0 && rc == 0){              // KL rider tensor 1 (16 units)
    float se = 0, sel = 0, sef = 0, sq = 0;
    for (int k = t; k < 512; k += 256){
      float f = c1_swc[k];
      float l = p.lap_c1[oc0 * 128 + k];
      float e = expf(l);
      se += e; sel += e * l; sef += e * f; sq += expf(f);
    }
    klAccum(se, sel, sef, sq, p.dstat + 1280 + 4);
  }
}

// ---- P1 riders: f_c2 writer + KL(t2); KL(t3) ------------------------------
__device__ void fc2Unit(int j, const Params& p){
  const int t = threadIdx.x;
  __shared__ float f2_saff[STAGE];
  __syncthreads();
  if (t < STAGE) f2_saff[t] = p.a_c2[t];
  float mn, mx; mmReduce(p.mmbuf, 2, mn, mx);
  const float rng = mx - mn;
  __syncthreads();
  float se = 0, sel = 0, sef = 0, sq = 0;
  for (int k = t; k < 576; k += 256){
    float nv = reconv(p.w_c2[j * 576 + k], mn, rng, f2_saff);
    p.f_c2[j * 576 + k] = nv;
    float l = p.lap_c2[j * 576 + k];
    float e = expf(l);
    se += e; sel += e * l; sef += e * nv; sq += expf(nv);
  }
  klAccum(se, sel, sef, sq, p.dstat + 1280 + 8);
}
__device__ void klt3Unit(int j, const Params& p){
  const int t = threadIdx.x;
  __shared__ float t3_saff[STAGE];
  __syncthreads();
  if (t < STAGE) t3_saff[t] = p.a_c3[t];
  float mn, mx; mmReduce(p.mmbuf, 3, mn, mx);
  const float rng = mx - mn;
  __syncthreads();
  float se = 0, sel = 0, sef = 0, sq = 0;
  for (int k = t; k < 1024; k += 256){
    float nv = reconv(p.w_c3[j * 1024 + k], mn, rng, t3_saff);
    float l = p.lap_c3[j * 1024 + k];
    float e = expf(l);
    se += e; sel += e * l; sef += e * nv; sq += expf(nv);
  }
  klAccum(se, sel, sef, sq, p.dstat + 1280 + 12);
}

// ---- P2 unit: bnpad half-channel (u in [0,512)) ---------------------------
__device__ void bnpadHalf(int u, const Params& p){
  const int a = u >> 1, half = u & 1;
  const int c = a & 63;
  __shared__ float bp_sc, bp_sb;
  __syncthreads();
  if (threadIdx.x == 0){
    double s  = p.dstat[512 + c] * (1.0 / 3136.0);
    double vr = p.dstat[576 + c] * (1.0 / 3136.0) - s * s;
    float scale = p.g1[c] * rsqrtf((float)vr + 1e-5f);
    bp_sc = scale; bp_sb = p.b1[c] - (float)s * scale;
  }
  __syncthreads();
  const float sc_ = bp_sc, bi_ = bp_sb;
  const float* src = p.T2 + (size_t)a * HW;
  float* dst = p.T2b + (size_t)a * 960;
  for (int i = half * 480 + threadIdx.x; i < half * 480 + 480; i += 256){
    int row = i >> 5, col = i & 31;
    float v = 0.0f;
    if (row >= 1 && row <= 28 && col >= 1 && col <= 28)
      v = fmaxf(src[(row - 1) * 28 + (col - 1)] * sc_ + bi_, 0.0f);
    dst[i] = v;
  }
}

// ---- P3 unit: mid3x3 (u in [0,512)) (R5 body) -----------------------------
__device__ void midUnit(int u, const Params& p){
  const int t = threadIdx.x;
  const int chunk = u & 3, og = (u >> 2) & 31, b = u >> 7;
  const int oc0 = og * 2;
  const float* wA = p.f_c2 + oc0 * 576;
  const float* wB = wA + 576;

  float v0 = 0, v1 = 0;
  const int px = chunk * 196 + t;
  if (t < 196){
    const int y = px / 28, xc = px - y * 28;
    const float* base = p.T2b + (size_t)b * 64 * 960 + y * 32 + xc;
    float c0 = 0, c1 = 0;
    #pragma unroll 2
    for (int c = 0; c < 64; c++){
      const float* pp = base + c * 960;
      float t0 = pp[0],  t1 = pp[1],  t2 = pp[2];
      float t3 = pp[32], t4 = pp[33], t5 = pp[34];
      float t6 = pp[64], t7 = pp[65], t8 = pp[66];
      const float* wa = wA + c * 9;
      const float* wb = wB + c * 9;
      c0 += fabsf(t0 - wa[0]) + fabsf(t1 - wa[1]) + fabsf(t2 - wa[2])
          + fabsf(t3 - wa[3]) + fabsf(t4 - wa[4]) + fabsf(t5 - wa[5])
          + fabsf(t6 - wa[6]) + fabsf(t7 - wa[7]) + fabsf(t8 - wa[8]);
      c1 += fabsf(t0 - wb[0]) + fabsf(t1 - wb[1]) + fabsf(t2 - wb[2])
          + fabsf(t3 - wb[3]) + fabsf(t4 - wb[4]) + fabsf(t5 - wb[5])
          + fabsf(t6 - wb[6]) + fabsf(t7 - wb[7]) + fabsf(t8 - wb[8]);
    }
    v0 = -c0; v1 = -c1;
    p.T3[((size_t)(b * 64 + oc0)) * HW + px]     = v0;
    p.T3[((size_t)(b * 64 + oc0 + 1)) * HW + px] = v1;
  }
  stats2(v0, v1, p.dstat + 640, p.dstat + 704, oc0);
}

// ---- P4 unit: back (u in [0,1024)) (R5 body) ------------------------------
__device__ void backUnit(int u, const Params& p){
  const int t = threadIdx.x;
  const int chunk = u & 3, og = (u >> 2) & 63, b = u >> 8;
  const int oc0 = og * 4;
  __shared__ float bk_sc[64], bk_sb[64], bk_sw[256], bk_saff[STAGE];
  __syncthreads();
  if (t < 64){
    double s  = p.dstat[640 + t] * (1.0 / 3136.0);
    double vr = p.dstat[704 + t] * (1.0 / 3136.0) - s * s;
    float scale = p.g2[t] * rsqrtf((float)vr + 1e-5f);
    bk_sc[t] = scale; bk_sb[t] = p.b2[t] - (float)s * scale;
  }
  if (t >= 128 && t < 128 + STAGE) bk_saff[t - 128] = p.a_c3[t - 128];
  float mn, mx; mmReduce(p.mmbuf, 3, mn, mx);
  const float rng = mx - mn;
  __syncthreads();
  bk_sw[t] = reconv(p.w_c3[oc0 * 64 + t], mn, rng, bk_saff);
  __syncthreads();

  const int px = chunk * 196 + t;
  float v0 = 0, v1 = 0, v2 = 0, v3 = 0;
  if (t < 196){
    const float* bp = p.T3 + (size_t)b * 64 * HW + px;
    float c0 = 0, c1 = 0, c2 = 0, c3 = 0;
    #pragma unroll 4
    for (int c = 0; c < 64; c++){
      float raw = bp[(size_t)c * HW];
      float vv = fmaxf(raw * bk_sc[c] + bk_sb[c], 0.0f);
      c0 += fabsf(vv - bk_sw[c]);
      c1 += fabsf(vv - bk_sw[64 + c]);
      c2 += fabsf(vv - bk_sw[128 + c]);
      c3 += fabsf(vv - bk_sw[192 + c]);
    }
    v0 = -c0; v1 = -c1; v2 = -c2; v3 = -c3;
    float* op = p.out + ((size_t)(b * 256 + oc0)) * HW + px;
    op[0] = v0; op[HW] = v1; op[2 * HW] = v2; op[3 * HW] = v3;
  }
  stats4(v0, v1, v2, v3, p.dstat + 768, p.dstat + 1024, oc0);
}

// =========================== the fused kernel ==============================
__global__ __launch_bounds__(256) void fused_kernel(Params p){
  cg::grid_group grid = cg::this_grid();
  const int blk = blockIdx.x, t = threadIdx.x;

  // ---- P0: minmax partials (blocks 0..63) + zero dstat ----
  if (t < 3 && blk * 3 + t < 1296) p.dstat[blk * 3 + t] = 0.0;
  if (blk < 64){
    const int tens = blk >> 4, slot = blk & 15;
    const float* w; int n;
    if      (tens == 0){ w = p.w_ds; n = 32768; }
    else if (tens == 1){ w = p.w_c1; n = 8192; }
    else if (tens == 2){ w = p.w_c2; n = 36864; }
    else               { w = p.w_c3; n = 16384; }
    float mn = 3.402823466e38f, mx = -3.402823466e38f;
    for (int i = slot * 256 + t; i < n; i += 4096){
      float v = w[i];
      mn = fminf(mn, v); mx = fmaxf(mx, v);
    }
    mn = blockMin4(mn); mx = blockMax4(mx);
    if (t == 0){
      p.mmbuf[tens * 32 + slot]      = mn;
      p.mmbuf[tens * 32 + 16 + slot] = mx;
    }
  }
  grid.sync();

  // ---- P1: ds(512) + c1peg(256) + f_c2(64) + klt3(16) ----
  if (blk < 256){
    c1Unit(blk, p);
    dsUnit(blk, p);
  } else {
    dsUnit(blk, p);
    int r = blk - 256;
    if (r < 64) fc2Unit(r, p);
    else if (r < 80) klt3Unit(r - 64, p);
  }
  grid.sync();

  // ---- P2: bnpad (512 half-channel units) ----
  bnpadHalf(blk, p);
  grid.sync();

  // ---- P3: mid3x3 (512 units) ----
  midUnit(blk, p);
  grid.sync();

  // ---- P4: back (1024 units, 2 per block) ----
  backUnit(blk, p);
  backUnit(blk + 512, p);
  grid.sync();

  // ---- P5: final (784 units over 512 blocks) + KL finalize ----
  __shared__ float s3c[256], s3b[256], sdc[256], sdb[256];
  __syncthreads();
  {
    double s  = p.dstat[768 + t] * (1.0 / 3136.0);
    double vr = p.dstat[1024 + t] * (1.0 / 3136.0) - s * s;
    float scale = p.g3[t] * rsqrtf((float)vr + 1e-5f);
    s3c[t] = scale; s3b[t] = p.b3[t] - (float)s * scale;
    s  = p.dstat[t] * (1.0 / 3136.0);
    vr = p.dstat[256 + t] * (1.0 / 3136.0) - s * s;
    scale = p.gds[t] * rsqrtf((float)vr + 1e-5f);
    sdc[t] = scale; sdb[t] = p.bds[t] - (float)s * scale;
  }
  __syncthreads();
  for (int rep = 0; rep < 2; rep++){
    int u = blk + rep * 512;
    if (u < 784){
      #pragma unroll
      for (int k = 0; k < 4; k++){
        int n = u * 1024 + k * 256 + t;
        int c = (n / HW) & 255;
        float h = p.out[n], aa = p.A[n];
        float r = fmaxf(aa * sdc[c] + sdb[c], 0.0f);
        p.out[n] = fmaxf(h * s3c[c] + s3b[c] + r, 0.0f);
      }
    }
  }
  if (blk == 0 && t == 0){
    const int ns[4] = {32768, 8192, 36864, 16384};
    float kl = 0.0f;
    #pragma unroll
    for (int q = 0; q < 4; q++){
      double se  = p.dstat[1280 + q * 4];
      double sel = p.dstat[1280 + q * 4 + 1];
      double sef = p.dstat[1280 + q * 4 + 2];
      double sq  = p.dstat[1280 + q * 4 + 3];
      kl += (float)((((sel - sef) / se) - log(se) + log(sq)) / (double)ns[q]);
    }
    p.out[802816] = kl;
  }
}

// ===========================================================================
extern "C" void kernel_launch(void* const* d_in, const int* in_sizes, int n_in,
                              void* d_out, int out_size, void* d_ws, size_t ws_size,
                              hipStream_t stream)
{
  float* ws = (float*)d_ws;

  Params p;
  p.x      = (const float*)d_in[0];
  p.w_ds   = (const float*)d_in[1];
  p.w_c1   = (const float*)d_in[2];
  p.w_c2   = (const float*)d_in[3];
  p.w_c3   = (const float*)d_in[4];
  p.a_ds   = (const float*)d_in[5];
  p.a_c1   = (const float*)d_in[6];
  p.a_c2   = (const float*)d_in[7];
  p.a_c3   = (const float*)d_in[8];
  p.peg_w  = (const float*)d_in[9];
  p.g1     = (const float*)d_in[10];
  p.b1     = (const float*)d_in[11];
  p.g2     = (const float*)d_in[12];
  p.b2     = (const float*)d_in[13];
  p.g3     = (const float*)d_in[14];
  p.b3     = (const float*)d_in[15];
  p.gds    = (const float*)d_in[16];
  p.bds    = (const float*)d_in[17];
  p.lap_ds = (const float*)d_in[18];
  p.lap_c1 = (const float*)d_in[19];
  p.lap_c2 = (const float*)d_in[20];
  p.lap_c3 = (const float*)d_in[21];

  p.f_c2  = ws;                        // 36864
  p.mmbuf = ws + 36864;                // 128
  p.dstat = (double*)(ws + 36992);     // 1296 doubles -> 2592 floats (pad 2688)
  p.A     = ws + 39680;                // 802816
  p.T2    = ws + 842496;               // 200704
  p.T3    = ws + 1043200;              // 200704
  p.T2b   = ws + 1243904;              // 245760
  p.out   = (float*)d_out;

  void* args[] = { &p };
  hipLaunchCooperativeKernel(reinterpret_cast<void*>(fused_kernel),
                             dim3(512), dim3(256), args, 0, stream);
}

// Round 9
// 173.634 us; speedup vs baseline: 2.6761x; 2.6761x over previous
//
#include <hip/hip_runtime.h>
#include <math.h>

// R9 = R5 verbatim (verified best: 171.8us). R6 (s_load weights), R7 (rider
// load-balancing), R8 (cooperative single-kernel, grid.sync ~60us/sync on
// gfx950!) all regressed. Six-dispatch structure with distributed recon is
// the empirical optimum; remaining time is dominated by the ~137us harness
// floor (268MB ws re-poison fills visible as 40us fillBufferAligned in every
// profile).

#define HW 784      // 28*28
#define NB 4
#define STAGE 100

// ---------------- wave/block reduction helpers (wave64) --------------------
__device__ __forceinline__ float wredMax(float v){
  for (int o = 32; o > 0; o >>= 1) v = fmaxf(v, __shfl_down(v, o, 64));
  return v;
}
__device__ __forceinline__ float wredMin(float v){
  for (int o = 32; o > 0; o >>= 1) v = fminf(v, __shfl_down(v, o, 64));
  return v;
}
__device__ __forceinline__ double wredSumD(double v){
  for (int o = 32; o > 0; o >>= 1) v += __shfl_down(v, o, 64);
  return v;
}

// blockDim = 256 (4 waves)
__device__ float blockMin4(float v){
  __shared__ float shn[4];
  __syncthreads();
  v = wredMin(v);
  if ((threadIdx.x & 63) == 0) shn[threadIdx.x >> 6] = v;
  __syncthreads();
  return fminf(fminf(shn[0], shn[1]), fminf(shn[2], shn[3]));
}
__device__ float blockMax4(float v){
  __shared__ float shx[4];
  __syncthreads();
  v = wredMax(v);
  if ((threadIdx.x & 63) == 0) shx[threadIdx.x >> 6] = v;
  __syncthreads();
  return fmaxf(fmaxf(shx[0], shx[1]), fmaxf(shx[2], shx[3]));
}

// ---- per-block BN stats: 4 channels, sum+sumsq, double atomics (256 thr) --
__device__ void stats4(float v0, float v1, float v2, float v3,
                       double* sumP, double* sqP, int oc0){
  __shared__ double sred[4][8];
  __syncthreads();
  const int w = threadIdx.x >> 6;
  float vv[4] = {v0, v1, v2, v3};
  #pragma unroll
  for (int i = 0; i < 4; i++){
    double d = (double)vv[i];
    double s = wredSumD(d);
    double q = wredSumD(d * d);
    if ((threadIdx.x & 63) == 0){ sred[w][i] = s; sred[w][4 + i] = q; }
  }
  __syncthreads();
  if (threadIdx.x < 8){
    double tot = sred[0][threadIdx.x] + sred[1][threadIdx.x]
               + sred[2][threadIdx.x] + sred[3][threadIdx.x];
    int i = threadIdx.x & 3;
    if (threadIdx.x < 4) atomicAdd(&sumP[oc0 + i], tot);
    else                 atomicAdd(&sqP[oc0 + i],  tot);
  }
}
__device__ void stats2(float v0, float v1, double* sumP, double* sqP, int oc0){
  __shared__ double sred2[4][4];
  __syncthreads();
  const int w = threadIdx.x >> 6;
  float vv[2] = {v0, v1};
  #pragma unroll
  for (int i = 0; i < 2; i++){
    double d = (double)vv[i];
    double s = wredSumD(d);
    double q = wredSumD(d * d);
    if ((threadIdx.x & 63) == 0){ sred2[w][i] = s; sred2[w][2 + i] = q; }
  }
  __syncthreads();
  if (threadIdx.x < 4){
    double tot = sred2[0][threadIdx.x] + sred2[1][threadIdx.x]
               + sred2[2][threadIdx.x] + sred2[3][threadIdx.x];
    int i = threadIdx.x & 1;
    if (threadIdx.x < 2) atomicAdd(&sumP[oc0 + i], tot);
    else                 atomicAdd(&sqP[oc0 + i],  tot);
  }
}

// ---- KL partial accumulation: 4 sums -> 4 double atomics (256 thr) --------
__device__ void klAccum(float se, float sel, float sef, float sq, double* dst){
  __shared__ double kls[4][4];
  __syncthreads();
  const int w = threadIdx.x >> 6;
  double a0 = wredSumD((double)se);
  double a1 = wredSumD((double)sel);
  double a2 = wredSumD((double)sef);
  double a3 = wredSumD((double)sq);
  if ((threadIdx.x & 63) == 0){
    kls[w][0] = a0; kls[w][1] = a1; kls[w][2] = a2; kls[w][3] = a3;
  }
  __syncthreads();
  if (threadIdx.x < 4){
    double tot = kls[0][threadIdx.x] + kls[1][threadIdx.x]
               + kls[2][threadIdx.x] + kls[3][threadIdx.x];
    atomicAdd(&dst[threadIdx.x], tot);
  }
}

// ---- bin reconstruction (reference op order; exact bin indices) -----------
__device__ __forceinline__ float reconv(float vv, float mn, float rng,
                                        const float* saff){
  float q = (vv - mn) / rng * 100.0f;
  int idx = (int)floorf(q);
  float nv = 0.0f;
  if (idx < STAGE){
    int ci = idx < 0 ? 0 : (idx > STAGE - 1 ? STAGE - 1 : idx);
    nv = vv * saff[ci];
  }
  return nv;
}

// ---- reduce 16 per-block minmax partials (race-free, no atomics) ----------
__device__ __forceinline__ void mmReduce(const float* mmbuf, int tens,
                                         float& mn, float& mx){
  mn = 3.402823466e38f; mx = -3.402823466e38f;
  #pragma unroll
  for (int k = 0; k < 16; k++){
    mn = fminf(mn, mmbuf[tens * 32 + k]);
    mx = fmaxf(mx, mmbuf[tens * 32 + 16 + k]);
  }
}

// --------------- K0: partial min/max of 4 weight tensors + zero stats ------
// grid = 64: tensor = blk>>4, slot = blk&15. Also zeroes dstat (1344 dbl).
// dstat layout: [0:256) ds_sum [256:512) ds_sq [512:576) bn1_s [576:640) bn1_q
//   [640:704) bn2_s [704:768) bn2_q [768:1024) bn3_s [1024:1280) bn3_q
//   [1280:1296) kl: tensor*4 + {se, sel, sef, sq}
__global__ __launch_bounds__(256) void minmax_kernel(
    const float* w0, int n0, const float* w1, int n1,
    const float* w2, int n2, const float* w3, int n3,
    float* mmbuf, double* dstat)
{
  if (threadIdx.x < 21) dstat[blockIdx.x * 21 + threadIdx.x] = 0.0;
  const int tens = blockIdx.x >> 4, slot = blockIdx.x & 15;
  const float* w; int n;
  if      (tens == 0){ w = w0; n = n0; }
  else if (tens == 1){ w = w1; n = n1; }
  else if (tens == 2){ w = w2; n = n2; }
  else               { w = w3; n = n3; }
  float mn = 3.402823466e38f, mx = -3.402823466e38f;
  for (int i = slot * 256 + threadIdx.x; i < n; i += 4096){
    float v = w[i];
    mn = fminf(mn, v); mx = fmaxf(mx, v);
  }
  mn = blockMin4(mn); mx = blockMax4(mx);
  if (threadIdx.x == 0){
    mmbuf[tens * 32 + slot]      = mn;
    mmbuf[tens * 32 + 16 + slot] = mx;
  }
}

// --------------- K1: front — adder_ds + (adder_c1+PEG) + riders ------------
// blocks [0,512): adder_ds, 8 oc, 196-px chunks (inline recon)
// blocks [512,768): adder_c1+peg, 4 oc, 7-row tile (inline recon)
// blocks [768,832): recon+write f_c2 row + KL(t2)
// blocks [832,848): KL(t3)
__global__ __launch_bounds__(256) void front_kernel(
    const float* __restrict__ x,
    const float* __restrict__ w_ds, const float* __restrict__ aff_ds,
    const float* __restrict__ lap_ds,
    const float* __restrict__ w_c1, const float* __restrict__ aff_c1,
    const float* __restrict__ lap_c1,
    const float* __restrict__ w_c2, const float* __restrict__ aff_c2,
    const float* __restrict__ lap_c2, float* __restrict__ f_c2,
    const float* __restrict__ w_c3, const float* __restrict__ aff_c3,
    const float* __restrict__ lap_c3,
    const float* __restrict__ peg_w, const float* __restrict__ mmbuf,
    float* __restrict__ A, float* __restrict__ T2, double* __restrict__ dS)
{
  const int t = threadIdx.x;
  if (blockIdx.x < 512){
    // ---------------- adder_ds ----------------
    const int a = blockIdx.x;
    const int chunk = a & 3, og = (a >> 2) & 31, b = a >> 7;
    const int oc0 = og * 8;
    __shared__ float saff[STAGE];
    __shared__ float sw[1024];
    if (t < STAGE) saff[t] = aff_ds[t];
    float mn, mx; mmReduce(mmbuf, 0, mn, mx);
    const float rng = mx - mn;
    __syncthreads();
    for (int k = t; k < 1024; k += 256)
      sw[k] = reconv(w_ds[oc0 * 128 + k], mn, rng, saff);
    __syncthreads();

    const int px = chunk * 196 + t;
    float v0=0,v1=0,v2=0,v3=0,v4=0,v5=0,v6=0,v7=0;
    if (t < 196){
      const float* xp = x + (size_t)b * 128 * HW + px;
      float c0=0,c1=0,c2=0,c3=0,c4=0,c5=0,c6=0,c7=0;
      #pragma unroll 4
      for (int c = 0; c < 128; c++){
        float xv = xp[(size_t)c * HW];
        c0 += fabsf(xv - sw[c]);
        c1 += fabsf(xv - sw[128 + c]);
        c2 += fabsf(xv - sw[256 + c]);
        c3 += fabsf(xv - sw[384 + c]);
        c4 += fabsf(xv - sw[512 + c]);
        c5 += fabsf(xv - sw[640 + c]);
        c6 += fabsf(xv - sw[768 + c]);
        c7 += fabsf(xv - sw[896 + c]);
      }
      v0=-c0; v1=-c1; v2=-c2; v3=-c3; v4=-c4; v5=-c5; v6=-c6; v7=-c7;
      float* op = A + ((size_t)(b * 256 + oc0)) * HW + px;
      op[0]=v0; op[HW]=v1; op[2*HW]=v2; op[3*HW]=v3;
      op[4*HW]=v4; op[5*HW]=v5; op[6*HW]=v6; op[7*HW]=v7;
    }
    stats4(v0, v1, v2, v3, dS + 0, dS + 256, oc0);
    stats4(v4, v5, v6, v7, dS + 0, dS + 256, oc0 + 4);

    if (b == 0 && chunk == 0){     // KL partial for tensor 0 (own slice)
      float se = 0, sel = 0, sef = 0, sq = 0;
      for (int k = t; k < 1024; k += 256){
        float l = lap_ds[oc0 * 128 + k];
        float e = expf(l);
        se += e; sel += e * l; sef += e * sw[k];
        sq += expf(sw[k]);
      }
      klAccum(se, sel, sef, sq, dS + 1280 + 0);
    }
  } else if (blockIdx.x < 768){
    // ---------------- adder_c1 + PEG ----------------
    const int a = blockIdx.x - 512;
    const int rc = a & 3, og = (a >> 2) & 15, b = a >> 6;
    const int oc0 = og * 4;
    __shared__ float saffc[STAGE];
    __shared__ float swc[512];
    __shared__ float swp[36];
    __shared__ float sT1[4][256];
    if (t < STAGE) saffc[t] = aff_c1[t];
    if (t >= 128 && t < 164) swp[t - 128] = peg_w[oc0 * 9 + (t - 128)];
    float mn, mx; mmReduce(mmbuf, 1, mn, mx);
    const float rng = mx - mn;
    __syncthreads();
    for (int k = t; k < 512; k += 256)
      swc[k] = reconv(w_c1[oc0 * 128 + k], mn, rng, saffc);
    __syncthreads();

    if (t < 252){
      const int rr = t / 28;
      const int col = t - rr * 28;
      const int wr = rc * 7 - 1 + rr;
      float tv0 = 0, tv1 = 0, tv2 = 0, tv3 = 0;
      if (wr >= 0 && wr < 28){
        const float* xp = x + (size_t)b * 128 * HW + wr * 28 + col;
        float c0 = 0, c1 = 0, c2 = 0, c3 = 0;
        #pragma unroll 4
        for (int c = 0; c < 128; c++){
          float xv = xp[(size_t)c * HW];
          c0 += fabsf(xv - swc[c]);
          c1 += fabsf(xv - swc[128 + c]);
          c2 += fabsf(xv - swc[256 + c]);
          c3 += fabsf(xv - swc[384 + c]);
        }
        tv0 = -c0; tv1 = -c1; tv2 = -c2; tv3 = -c3;
      }
      sT1[0][t] = tv0; sT1[1][t] = tv1; sT1[2][t] = tv2; sT1[3][t] = tv3;
    }
    __syncthreads();
    float v0 = 0, v1 = 0, v2 = 0, v3 = 0;
    if (t < 196){
      const int r = t / 28, col = t - r * 28;
      float c0 = 0, c1 = 0, c2 = 0, c3 = 0;
      #pragma unroll
      for (int ky = 0; ky < 3; ky++){
        #pragma unroll
        for (int kx = 0; kx < 3; kx++){
          int cc = col + kx - 1;
          bool ok = (cc >= 0) && (cc < 28);
          int idx = ok ? ((r + ky) * 28 + cc) : 0;
          float p0 = ok ? sT1[0][idx] : 0.0f;
          float p1 = ok ? sT1[1][idx] : 0.0f;
          float p2 = ok ? sT1[2][idx] : 0.0f;
          float p3 = ok ? sT1[3][idx] : 0.0f;
          int wk = ky * 3 + kx;
          c0 += fabsf(p0 - swp[wk]);
          c1 += fabsf(p1 - swp[9 + wk]);
          c2 += fabsf(p2 - swp[18 + wk]);
          c3 += fabsf(p3 - swp[27 + wk]);
        }
      }
      v0 = -c0; v1 = -c1; v2 = -c2; v3 = -c3;
      const int opx = (rc * 7 + r) * 28 + col;
      float* op = T2 + ((size_t)(b * 64 + oc0)) * HW + opx;
      op[0] = v0; op[HW] = v1; op[2 * HW] = v2; op[3 * HW] = v3;
    }
    stats4(v0, v1, v2, v3, dS + 512, dS + 576, oc0);

    if (b == 0 && rc == 0){        // KL partial for tensor 1
      float se = 0, sel = 0, sef = 0, sq = 0;
      for (int k = t; k < 512; k += 256){
        float l = lap_c1[oc0 * 128 + k];
        float e = expf(l);
        se += e; sel += e * l; sef += e * swc[k];
        sq += expf(swc[k]);
      }
      klAccum(se, sel, sef, sq, dS + 1280 + 4);
    }
  } else if (blockIdx.x < 832){
    // ---------------- f_c2 writer + KL (tensor 2) ----------------
    const int j = blockIdx.x - 768;          // oc row 0..63, 576 elems
    __shared__ float saff2[STAGE];
    if (t < STAGE) saff2[t] = aff_c2[t];
    float mn, mx; mmReduce(mmbuf, 2, mn, mx);
    const float rng = mx - mn;
    __syncthreads();
    float se = 0, sel = 0, sef = 0, sq = 0;
    for (int k = t; k < 576; k += 256){
      float nv = reconv(w_c2[j * 576 + k], mn, rng, saff2);
      f_c2[j * 576 + k] = nv;
      float l = lap_c2[j * 576 + k];
      float e = expf(l);
      se += e; sel += e * l; sef += e * nv; sq += expf(nv);
    }
    klAccum(se, sel, sef, sq, dS + 1280 + 8);
  } else {
    // ---------------- KL (tensor 3) ----------------
    const int j = blockIdx.x - 832;          // slice of 1024
    __shared__ float saff3[STAGE];
    if (t < STAGE) saff3[t] = aff_c3[t];
    float mn, mx; mmReduce(mmbuf, 3, mn, mx);
    const float rng = mx - mn;
    __syncthreads();
    float se = 0, sel = 0, sef = 0, sq = 0;
    for (int k = t; k < 1024; k += 256){
      float nv = reconv(w_c3[j * 1024 + k], mn, rng, saff3);
      float l = lap_c3[j * 1024 + k];
      float e = expf(l);
      se += e; sel += e * l; sef += e * nv; sq += expf(nv);
    }
    klAccum(se, sel, sef, sq, dS + 1280 + 12);
  }
}

// --------------- K2: bn1 finalize + apply + relu -> padded T2b -------------
// T2b: (b, c, row 0..29, col 0..31); interior [1..28]^2 = relu(bn1(T2)).
__global__ __launch_bounds__(256) void bnapply_pad_kernel(
    const float* __restrict__ T2, float* __restrict__ T2b,
    const float* __restrict__ g1, const float* __restrict__ b1,
    const double* __restrict__ dS)
{
  const int a = blockIdx.x;           // b*64 + c
  const int c = a & 63;
  __shared__ float ssc, ssb;
  if (threadIdx.x == 0){
    double s  = dS[512 + c] * (1.0 / 3136.0);
    double vr = dS[576 + c] * (1.0 / 3136.0) - s * s;
    float scale = g1[c] * rsqrtf((float)vr + 1e-5f);
    ssc = scale; ssb = b1[c] - (float)s * scale;
  }
  __syncthreads();
  const float sc_ = ssc, bi_ = ssb;
  const float* src = T2 + (size_t)a * HW;
  float* dst = T2b + (size_t)a * 960;
  for (int i = threadIdx.x; i < 960; i += 256){
    int row = i >> 5, col = i & 31;
    float v = 0.0f;
    if (row >= 1 && row <= 28 && col >= 1 && col <= 28)
      v = fmaxf(src[(row - 1) * 28 + (col - 1)] * sc_ + bi_, 0.0f);
    dst[i] = v;
  }
}

// --------------- K3: adder 3x3 over padded T2b -----------------------------
__global__ __launch_bounds__(256) void mid3x3_kernel(
    const float* __restrict__ T2b, const float* __restrict__ f_c2,
    float* __restrict__ T3, double* __restrict__ dS)
{
  const int t = threadIdx.x;
  const int a = blockIdx.x;
  const int chunk = a & 3, og = (a >> 2) & 31, b = a >> 7;
  const int oc0 = og * 2;
  const float* __restrict__ wA = f_c2 + oc0 * 576;
  const float* __restrict__ wB = wA + 576;

  float v0 = 0, v1 = 0;
  const int px = chunk * 196 + t;
  if (t < 196){
    const int y = px / 28, xc = px - y * 28;
    const float* base = T2b + (size_t)b * 64 * 960 + y * 32 + xc;
    float c0 = 0, c1 = 0;
    #pragma unroll 2
    for (int c = 0; c < 64; c++){
      const float* p = base + c * 960;
      float t0 = p[0],  t1 = p[1],  t2 = p[2];
      float t3 = p[32], t4 = p[33], t5 = p[34];
      float t6 = p[64], t7 = p[65], t8 = p[66];
      const float* wa = wA + c * 9;
      const float* wb = wB + c * 9;
      c0 += fabsf(t0 - wa[0]) + fabsf(t1 - wa[1]) + fabsf(t2 - wa[2])
          + fabsf(t3 - wa[3]) + fabsf(t4 - wa[4]) + fabsf(t5 - wa[5])
          + fabsf(t6 - wa[6]) + fabsf(t7 - wa[7]) + fabsf(t8 - wa[8]);
      c1 += fabsf(t0 - wb[0]) + fabsf(t1 - wb[1]) + fabsf(t2 - wb[2])
          + fabsf(t3 - wb[3]) + fabsf(t4 - wb[4]) + fabsf(t5 - wb[5])
          + fabsf(t6 - wb[6]) + fabsf(t7 - wb[7]) + fabsf(t8 - wb[8]);
    }
    v0 = -c0; v1 = -c1;
    T3[((size_t)(b * 64 + oc0)) * HW + px]     = v0;
    T3[((size_t)(b * 64 + oc0 + 1)) * HW + px] = v1;
  }
  stats2(v0, v1, dS + 640, dS + 704, oc0);
}

// --------------- K4: adder 1x1 64->256 (bn2 inline, inline recon) ----------
__global__ __launch_bounds__(256) void back_kernel(
    const float* __restrict__ T3, const float* __restrict__ w_c3,
    const float* __restrict__ aff_c3, const float* __restrict__ mmbuf,
    const float* __restrict__ g2, const float* __restrict__ b2,
    float* __restrict__ out, double* __restrict__ dS)
{
  const int t = threadIdx.x;
  const int a = blockIdx.x;
  const int chunk = a & 3, og = (a >> 2) & 63, b = a >> 8;
  const int oc0 = og * 4;
  __shared__ float ssc[64], ssb[64], sw[256], saff[STAGE];
  if (t < 64){
    double s  = dS[640 + t] * (1.0 / 3136.0);
    double vr = dS[704 + t] * (1.0 / 3136.0) - s * s;
    float scale = g2[t] * rsqrtf((float)vr + 1e-5f);
    ssc[t] = scale; ssb[t] = b2[t] - (float)s * scale;
  }
  if (t >= 128 && t < 128 + STAGE) saff[t - 128] = aff_c3[t - 128];
  float mn, mx; mmReduce(mmbuf, 3, mn, mx);
  const float rng = mx - mn;
  __syncthreads();
  sw[t] = reconv(w_c3[oc0 * 64 + t], mn, rng, saff);
  __syncthreads();

  const int px = chunk * 196 + t;
  float v0 = 0, v1 = 0, v2 = 0, v3 = 0;
  if (t < 196){
    const float* bp = T3 + (size_t)b * 64 * HW + px;
    float c0 = 0, c1 = 0, c2 = 0, c3 = 0;
    #pragma unroll 4
    for (int c = 0; c < 64; c++){
      float raw = bp[(size_t)c * HW];
      float vv = fmaxf(raw * ssc[c] + ssb[c], 0.0f);
      c0 += fabsf(vv - sw[c]);
      c1 += fabsf(vv - sw[64 + c]);
      c2 += fabsf(vv - sw[128 + c]);
      c3 += fabsf(vv - sw[192 + c]);
    }
    v0 = -c0; v1 = -c1; v2 = -c2; v3 = -c3;
    float* op = out + ((size_t)(b * 256 + oc0)) * HW + px;
    op[0] = v0; op[HW] = v1; op[2 * HW] = v2; op[3 * HW] = v3;
  }
  stats4(v0, v1, v2, v3, dS + 768, dS + 1024, oc0);
}

// --------------- K5: bn3 + bnds finalize, residual, relu, kl ---------------
__global__ __launch_bounds__(256) void final_kernel(
    float* __restrict__ out, const float* __restrict__ A,
    const float* __restrict__ g3, const float* __restrict__ b3,
    const float* __restrict__ gds, const float* __restrict__ bds,
    const double* __restrict__ dS)
{
  __shared__ float s3c[256], s3b[256], sdc[256], sdb[256];
  const int t = threadIdx.x;
  {
    double s  = dS[768 + t] * (1.0 / 3136.0);
    double vr = dS[1024 + t] * (1.0 / 3136.0) - s * s;
    float scale = g3[t] * rsqrtf((float)vr + 1e-5f);
    s3c[t] = scale; s3b[t] = b3[t] - (float)s * scale;
    s  = dS[t] * (1.0 / 3136.0);
    vr = dS[256 + t] * (1.0 / 3136.0) - s * s;
    scale = gds[t] * rsqrtf((float)vr + 1e-5f);
    sdc[t] = scale; sdb[t] = bds[t] - (float)s * scale;
  }
  __syncthreads();
  #pragma unroll
  for (int k = 0; k < 4; k++){
    int n = blockIdx.x * 1024 + k * 256 + t;
    int c = (n / HW) & 255;
    float h = out[n], aa = A[n];
    float r = fmaxf(aa * sdc[c] + sdb[c], 0.0f);
    out[n] = fmaxf(h * s3c[c] + s3b[c] + r, 0.0f);
  }
  if (blockIdx.x == 0 && t == 0){
    const int ns[4] = {32768, 8192, 36864, 16384};
    float kl = 0.0f;
    #pragma unroll
    for (int q = 0; q < 4; q++){
      double se  = dS[1280 + q * 4];
      double sel = dS[1280 + q * 4 + 1];
      double sef = dS[1280 + q * 4 + 2];
      double sq  = dS[1280 + q * 4 + 3];
      kl += (float)((((sel - sef) / se) - log(se) + log(sq)) / (double)ns[q]);
    }
    out[802816] = kl;
  }
}

// ===========================================================================
extern "C" void kernel_launch(void* const* d_in, const int* in_sizes, int n_in,
                              void* d_out, int out_size, void* d_ws, size_t ws_size,
                              hipStream_t stream)
{
  const float* x      = (const float*)d_in[0];
  const float* sw_ds  = (const float*)d_in[1];
  const float* sw_c1  = (const float*)d_in[2];
  const float* sw_c2  = (const float*)d_in[3];
  const float* sw_c3  = (const float*)d_in[4];
  const float* a_ds   = (const float*)d_in[5];
  const float* a_c1   = (const float*)d_in[6];
  const float* a_c2   = (const float*)d_in[7];
  const float* a_c3   = (const float*)d_in[8];
  const float* peg_w  = (const float*)d_in[9];
  const float* bn1_g  = (const float*)d_in[10];
  const float* bn1_b  = (const float*)d_in[11];
  const float* bn2_g  = (const float*)d_in[12];
  const float* bn2_b  = (const float*)d_in[13];
  const float* bn3_g  = (const float*)d_in[14];
  const float* bn3_b  = (const float*)d_in[15];
  const float* bnds_g = (const float*)d_in[16];
  const float* bnds_b = (const float*)d_in[17];
  const float* lap_ds = (const float*)d_in[18];
  const float* lap_c1 = (const float*)d_in[19];
  const float* lap_c2 = (const float*)d_in[20];
  const float* lap_c3 = (const float*)d_in[21];

  float* ws    = (float*)d_ws;
  float* f_c2  = ws;                        // 36864
  float* mmbuf = ws + 36864;                // 128
  double* dstat= (double*)(ws + 36992);     // 1344 doubles = 2688 floats
  float* A     = ws + 39680;                // 802816
  float* T2    = ws + 842496;               // 200704
  float* T3    = ws + 1043200;              // 200704
  float* T2b   = ws + 1243904;              // 245760

  float* out = (float*)d_out;

  minmax_kernel<<<64, 256, 0, stream>>>(
      sw_ds, 32768, sw_c1, 8192, sw_c2, 36864, sw_c3, 16384, mmbuf, dstat);

  front_kernel<<<848, 256, 0, stream>>>(
      x, sw_ds, a_ds, lap_ds, sw_c1, a_c1, lap_c1,
      sw_c2, a_c2, lap_c2, f_c2, sw_c3, a_c3, lap_c3,
      peg_w, mmbuf, A, T2, dstat);

  bnapply_pad_kernel<<<256, 256, 0, stream>>>(T2, T2b, bn1_g, bn1_b, dstat);

  mid3x3_kernel<<<512, 256, 0, stream>>>(T2b, f_c2, T3, dstat);

  back_kernel<<<1024, 256, 0, stream>>>(T3, sw_c3, a_c3, mmbuf,
                                        bn2_g, bn2_b, out, dstat);

  final_kernel<<<784, 256, 0, stream>>>(out, A, bn3_g, bn3_b, bnds_g, bnds_b,
                                        dstat);
}